// Round 3
// baseline (3425.204 us; speedup 1.0000x reference)
//
#include <hip/hip_runtime.h>
#include <hip/hip_bf16.h>

#define Bb 512
#define Dd 1024
#define Hh 2048
#define BH_ (Bb*Hh)
#define BD_ (Bb*Dd)

typedef unsigned short u16;
typedef __attribute__((ext_vector_type(8))) short short8;
typedef __attribute__((ext_vector_type(4))) float f32x4;

enum { M_F32 = 0, M_IN, M_SIG, M_SQRELU, M_OUT, M_DRIFT, M_FINAL };

#define GLL(gp, lp) __builtin_amdgcn_global_load_lds( \
    (const __attribute__((address_space(1))) void*)(gp), \
    (__attribute__((address_space(3))) void*)(lp), 16, 0, 0)

struct GemmP {
    const u16* A[3];
    const u16* W[3];     // transposed weights, N x K, bf16
    void* dst[3];
    int mode[3];
    int M, N, K;
    const int* done;
    // epilogue extras
    const float* bias;
    const float* mk; const float* mv; const float* mr; const float* mk2v; const float* mr2v;
    const float* xx; const float* cc;     // planar shadow state (loop)
    const float* lstate;                  // original interleaved state (final) or null
    float* liF;                           // Li plane (loop)
    float* stateOut;                      // d_out next_state base (final)
    u16 *o1, *o2, *o3, *o4, *o5;          // Xk,Xv,Xr,Xk2,Xr2
    const float* f1; const float* f2;     // Tm, R2
    float* drift; float* accAbs; float* accSq;
    float* scal; int nticket;             // ticket-folded stepfin (M_DRIFT only)
    const float* enc; const float* bout; float* dout;
};

// ---- 128x128x64 bf16 MFMA GEMM, global_load_lds staging, XOR-swizzled LDS ----
__global__ __launch_bounds__(256) void gemm128(GemmP p) {
    if (p.done && *(volatile const int*)p.done) return;
    const int z = blockIdx.z;
    const u16* __restrict__ A = p.A[z];
    const u16* __restrict__ W = p.W[z];
    const int Kd = p.K;
    const int m0 = blockIdx.y * 128, n0 = blockIdx.x * 128;

    __shared__ alignas(16) u16 As[128 * 64];
    __shared__ alignas(16) u16 Bs[128 * 64];

    const int t = threadIdx.x;
    const int l = t & 63, w = t >> 6;
    const int lane16 = l & 15, quad = l >> 4;
    const int wm = w & 1, wn = w >> 1;
    const int srow = t >> 3;     // 0..31 staging row within 32-row slab
    const int spos = t & 7;      // 16B chunk position within row

    f32x4 zero = {0.f, 0.f, 0.f, 0.f};
    f32x4 acc[4][4];
#pragma unroll
    for (int i = 0; i < 4; ++i)
#pragma unroll
        for (int j = 0; j < 4; ++j) acc[i][j] = zero;

    for (int k0 = 0; k0 < Kd; k0 += 64) {
#pragma unroll
        for (int j = 0; j < 4; ++j) {
            const int r = j * 32 + srow;                 // tile-local row 0..127
            const int ch = spos ^ (r & 7);               // swizzled source chunk
            GLL(A + (size_t)(m0 + r) * Kd + k0 + ch * 8, &As[r * 64 + spos * 8]);
            GLL(W + (size_t)(n0 + r) * Kd + k0 + ch * 8, &Bs[r * 64 + spos * 8]);
        }
        __syncthreads();   // drains vmcnt(0): LDS writes complete
#pragma unroll
        for (int kc = 0; kc < 64; kc += 32) {
            short8 af[4], bf[4];
            const int chb = (kc >> 3) + quad;            // logical chunk 0..7
#pragma unroll
            for (int sm = 0; sm < 4; ++sm) {
                const int r = wm * 64 + sm * 16 + lane16;
                af[sm] = *(const short8*)(const void*)&As[r * 64 + (chb ^ (r & 7)) * 8];
            }
#pragma unroll
            for (int sn = 0; sn < 4; ++sn) {
                const int r = wn * 64 + sn * 16 + lane16;
                bf[sn] = *(const short8*)(const void*)&Bs[r * 64 + (chb ^ (r & 7)) * 8];
            }
#pragma unroll
            for (int sm = 0; sm < 4; ++sm)
#pragma unroll
                for (int sn = 0; sn < 4; ++sn)
                    acc[sm][sn] = __builtin_amdgcn_mfma_f32_16x16x32_bf16(af[sm], bf[sn], acc[sm][sn], 0, 0, 0);
        }
        __syncthreads();
    }

    const int mode = p.mode[z];
    float sabs = 0.f, ssq = 0.f;
#pragma unroll
    for (int sm = 0; sm < 4; ++sm)
#pragma unroll
        for (int sn = 0; sn < 4; ++sn)
#pragma unroll
            for (int i = 0; i < 4; ++i) {
                const int m = m0 + wm * 64 + sm * 16 + quad * 4 + i;
                const int n = n0 + wn * 64 + sn * 16 + lane16;
                const size_t idx = (size_t)m * p.N + n;
                const float v = acc[sm][sn][i];
                if (mode == M_F32) {
                    ((float*)p.dst[z])[idx] = v;
                } else if (mode == M_IN) {
                    float li = fminf(fmaxf(v + p.bias[n], -50.f), 50.f);
                    float xxv, ccv;
                    if (p.lstate) { xxv = p.lstate[idx * 5 + 0]; ccv = p.lstate[idx * 5 + 4]; }
                    else { xxv = p.xx[idx]; ccv = p.cc[idx]; }
                    float mk = p.mk[n], mv = p.mv[n], mr = p.mr[n], mk2 = p.mk2v[n], mr2 = p.mr2v[n];
                    ((__hip_bfloat16*)p.o1)[idx] = __float2bfloat16(li * mk + xxv * (1.f - mk));
                    ((__hip_bfloat16*)p.o2)[idx] = __float2bfloat16(li * mv + xxv * (1.f - mv));
                    ((__hip_bfloat16*)p.o3)[idx] = __float2bfloat16(li * mr + xxv * (1.f - mr));
                    ((__hip_bfloat16*)p.o4)[idx] = __float2bfloat16(li * mk2 + ccv * (1.f - mk2));
                    ((__hip_bfloat16*)p.o5)[idx] = __float2bfloat16(li * mr2 + ccv * (1.f - mr2));
                    if (p.lstate) { p.stateOut[idx * 5 + 0] = li; p.stateOut[idx * 5 + 4] = li; }
                    else p.liF[idx] = li;
                } else if (mode == M_SIG) {
                    ((float*)p.dst[z])[idx] = 1.f / (1.f + __expf(-v));
                } else if (mode == M_SQRELU) {
                    float r = fmaxf(v, 0.f);
                    ((__hip_bfloat16*)p.dst[z])[idx] = __float2bfloat16(r * r);
                } else if (mode == M_OUT) {
                    ((__hip_bfloat16*)p.dst[z])[idx] = __float2bfloat16(p.f1[idx] + p.f2[idx] * v);
                } else if (mode == M_DRIFT) {
                    float d = tanhf(v);
                    float nd = fminf(fmaxf(p.drift[idx] + d, -5.f), 5.f);
                    p.drift[idx] = nd;
                    sabs += fabsf(d);
                    ssq += nd * nd;
                } else { // M_FINAL
                    p.dout[idx] = p.enc[idx] + v + p.bout[n];
                }
            }
    if (mode == M_DRIFT) {
#pragma unroll
        for (int off = 32; off > 0; off >>= 1) {
            sabs += __shfl_down(sabs, off, 64);
            ssq += __shfl_down(ssq, off, 64);
        }
        if (l == 0) { atomicAdd(p.accAbs, sabs); atomicAdd(p.accSq, ssq); }
        __syncthreads();
        if (t == 0) {   // last-block ticket performs the per-step scalar finalize
            __threadfence();
            int v = atomicAdd((int*)(p.scal + 5), 1);
            if (v == p.nticket - 1) {
                volatile float* s = p.scal;
                float hinge = fminf(fmaxf(s[4] / (float)Bb - 0.1f, 0.f), 100.f);
                s[1] = s[1] + hinge;
                s[2] = s[2] + 1.f;
                if (s[3] / (float)BD_ < 0.01f) ((volatile int*)p.scal)[0] = 1;
                s[3] = 0.f; s[4] = 0.f;
                ((volatile int*)p.scal)[5] = 0;
            }
        }
    }
}

// ---------------- transpose f32 (KxN) -> bf16 (NxK) ----------------
__global__ void transposeW(const float* __restrict__ src, u16* __restrict__ dst, int K, int N) {
    __shared__ float tile[32][33];
    int kt = blockIdx.y * 32, nt = blockIdx.x * 32;
    int tx = threadIdx.x, ty = threadIdx.y;
#pragma unroll
    for (int j = 0; j < 4; j++)
        tile[ty + j * 8][tx] = src[(size_t)(kt + ty + j * 8) * N + nt + tx];
    __syncthreads();
    __hip_bfloat16* d = (__hip_bfloat16*)dst;
#pragma unroll
    for (int j = 0; j < 4; j++)
        d[(size_t)(nt + ty + j * 8) * K + kt + tx] = __float2bfloat16(tile[tx][ty + j * 8]);
}

// ---------------- per-call init: planarize state, copy drift, zero scalars ----------------
__global__ void initstate(const float* __restrict__ lstate, const float* __restrict__ idrift,
                          float* xx, float* aa, float* bb, float* pp, float* cc,
                          float* drift, float* scal) {
    int i = blockIdx.x * 256 + threadIdx.x;
    if (i < BH_) {
        const float* s = lstate + (size_t)i * 5;
        xx[i] = s[0]; aa[i] = s[1]; bb[i] = s[2]; pp[i] = s[3]; cc[i] = s[4];
    }
    if (i < BD_) drift[i] = idrift[i];
    if (i == 0) {
        ((int*)scal)[0] = 0; scal[1] = 0.f; scal[2] = 0.f; scal[3] = 0.f; scal[4] = 0.f;
        ((int*)scal)[5] = 0;
    }
}

// ---------------- build A = [enc, sc + drift] in bf16 ----------------
__global__ void prep(const float* __restrict__ enc, const float* __restrict__ sc,
                     const float* __restrict__ drift, u16* __restrict__ Acat, const int* done) {
    if (done && *(volatile const int*)done) return;
    int i = blockIdx.x * 256 + threadIdx.x;
    if (i >= BD_) return;
    int m = i >> 10, d = i & 1023;
    __hip_bfloat16* Ab = (__hip_bfloat16*)Acat;
    Ab[(size_t)m * 2048 + d] = __float2bfloat16(enc[i]);
    Ab[(size_t)m * 2048 + 1024 + d] = __float2bfloat16(sc[i] + drift[i]);
}

// ---------------- RWKV wkv + state update ----------------
__global__ void mix1(const float* __restrict__ Kp, const float* __restrict__ Vp,
                     const float* __restrict__ Rp,
                     float* aa, float* bb, float* pp, float* xx, float* cc,
                     const float* __restrict__ Li,
                     const float* __restrict__ tf, const float* __restrict__ td,
                     u16* __restrict__ rwkv,
                     const float* __restrict__ lstate, float* stateOut,
                     const int* done) {
    if (done && *(volatile const int*)done) return;
    int i = blockIdx.x * 256 + threadIdx.x;
    if (i >= BH_) return;
    int h = i & (Hh - 1);
    float k = Kp[i], v = Vp[i], rpre = Rp[i];
    float a, b, P;
    if (lstate) { a = lstate[(size_t)i * 5 + 1]; b = lstate[(size_t)i * 5 + 2]; P = lstate[(size_t)i * 5 + 3]; }
    else { a = aa[i]; b = bb[i]; P = pp[i]; }
    float r = 1.f / (1.f + __expf(-rpre));
    float ww = tf[h] + k;
    float q = fmaxf(P, ww);
    float e1 = __expf(P - q), e2 = __expf(ww - q);
    float wkv = (e1 * a + e2 * v) / (e1 * b + e2);
    ((__hip_bfloat16*)rwkv)[i] = __float2bfloat16(r * wkv);
    float ww2 = P - __expf(td[h]);
    float q2 = fmaxf(ww2, k);
    float e1b = __expf(ww2 - q2), e2b = __expf(k - q2);
    float na = fminf(fmaxf(e1b * a + e2b * v, -50.f), 50.f);
    float nb = fminf(fmaxf(e1b * b + e2b, -50.f), 50.f);
    float nq = fminf(fmaxf(q2, -50.f), 50.f);
    if (lstate) {
        stateOut[(size_t)i * 5 + 1] = na; stateOut[(size_t)i * 5 + 2] = nb; stateOut[(size_t)i * 5 + 3] = nq;
    } else {
        aa[i] = na; bb[i] = nb; pp[i] = nq;
        float li = Li[i];
        xx[i] = li; cc[i] = li;
    }
}

// ---------------- tail: commitment scalar + drift copy ----------------
__global__ void tailk(const float* __restrict__ scal, const float* __restrict__ drift, float* __restrict__ dout) {
    int i = blockIdx.x * 256 + threadIdx.x;
    const size_t OC = (size_t)BD_ + (size_t)5 * BH_;
    if (i == 0) dout[OC] = scal[1] / fmaxf(scal[2], 1.f);
    if (i < BD_) dout[OC + 1 + i] = drift[i];
}

extern "C" void kernel_launch(void* const* d_in, const int* in_sizes, int n_in,
                              void* d_out, int out_size, void* d_ws, size_t ws_size,
                              hipStream_t stream) {
    const float* enc    = (const float*)d_in[0];
    const float* sc     = (const float*)d_in[1];
    const float* lstate = (const float*)d_in[2];
    const float* idrift = (const float*)d_in[3];
    const float* Win    = (const float*)d_in[4];
    const float* b_in   = (const float*)d_in[5];
    const float* Wdrift = (const float*)d_in[6];
    const float* Wout   = (const float*)d_in[7];
    const float* b_out  = (const float*)d_in[8];
    const float* mix_k  = (const float*)d_in[9];
    const float* mix_v  = (const float*)d_in[10];
    const float* mix_r  = (const float*)d_in[11];
    const float* mix_k2 = (const float*)d_in[12];
    const float* mix_r2 = (const float*)d_in[13];
    const float* tdec   = (const float*)d_in[14];
    const float* tfirst = (const float*)d_in[15];
    const float* Wk  = (const float*)d_in[16];
    const float* Wv  = (const float*)d_in[17];
    const float* Wr  = (const float*)d_in[18];
    const float* Wo  = (const float*)d_in[19];
    const float* Wk2 = (const float*)d_in[20];
    const float* Wv2 = (const float*)d_in[21];
    const float* Wr2 = (const float*)d_in[22];
    float* dout = (float*)d_out;

    const size_t BHs = (size_t)Bb * Hh;
    const size_t BDs = (size_t)Bb * Dd;

    const size_t need_f32 = 9 * BHs + BDs + 16;
    const size_t need_u16 = (size_t)2 * Dd * Hh + 7 * (size_t)Hh * Hh + 2 * (size_t)Hh * Dd + 8 * BHs;
    const size_t need_bytes = need_f32 * 4 + need_u16 * 2;
    if (ws_size < need_bytes) return;

    float* f = (float*)d_ws;
    float* xx  = f;
    float* aa  = xx + BHs;
    float* bbp = aa + BHs;
    float* ppp = bbp + BHs;
    float* cc  = ppp + BHs;
    float* Li  = cc + BHs;
    float* Kp  = Li + BHs;
    float* Vp  = Kp + BHs;
    float* Rp  = Vp + BHs;
    float* Tm  = Kp;    // alias: Kp dead after mix1, Tm written in p3
    float* R2  = Vp;    // alias: Vp dead after mix1, R2 written in p3
    float* drift = Rp + BHs;
    float* scal  = drift + BDs;
    u16* u = (u16*)(scal + 16);
    u16* WinT  = u; u += (size_t)2 * Dd * Hh;
    u16* WkT   = u; u += (size_t)Hh * Hh;
    u16* WvT   = u; u += (size_t)Hh * Hh;
    u16* WrT   = u; u += (size_t)Hh * Hh;
    u16* WoT   = u; u += (size_t)Hh * Hh;
    u16* Wk2T  = u; u += (size_t)Hh * Hh;
    u16* Wv2T  = u; u += (size_t)Hh * Hh;
    u16* Wr2T  = u; u += (size_t)Hh * Hh;
    u16* WdT   = u; u += (size_t)Hh * Dd;
    u16* WoutT = u; u += (size_t)Hh * Dd;
    u16* Acat = u; u += BHs;
    u16* Xk   = u; u += BHs;
    u16* Xv   = u; u += BHs;
    u16* Xr   = u; u += BHs;
    u16* Xk2  = u; u += BHs;
    u16* Xr2  = u; u += BHs;
    u16* Rw   = u; u += BHs;
    u16* Kk   = u; u += BHs;
    u16* Ob   = Acat;   // alias: Acat read only by p1; Ob written at p4, read at p5

    int* doneptr = (int*)scal;
    float* accAbs = scal + 3;
    float* accSq  = scal + 4;

    dim3 tb(32, 8);
    transposeW<<<dim3(Hh / 32, (2 * Dd) / 32), tb, 0, stream>>>(Win, WinT, 2 * Dd, Hh);
    transposeW<<<dim3(Hh / 32, Hh / 32), tb, 0, stream>>>(Wk,  WkT,  Hh, Hh);
    transposeW<<<dim3(Hh / 32, Hh / 32), tb, 0, stream>>>(Wv,  WvT,  Hh, Hh);
    transposeW<<<dim3(Hh / 32, Hh / 32), tb, 0, stream>>>(Wr,  WrT,  Hh, Hh);
    transposeW<<<dim3(Hh / 32, Hh / 32), tb, 0, stream>>>(Wo,  WoT,  Hh, Hh);
    transposeW<<<dim3(Hh / 32, Hh / 32), tb, 0, stream>>>(Wk2, Wk2T, Hh, Hh);
    transposeW<<<dim3(Hh / 32, Hh / 32), tb, 0, stream>>>(Wv2, Wv2T, Hh, Hh);
    transposeW<<<dim3(Hh / 32, Hh / 32), tb, 0, stream>>>(Wr2, Wr2T, Hh, Hh);
    transposeW<<<dim3(Dd / 32, Hh / 32), tb, 0, stream>>>(Wdrift, WdT, Hh, Dd);
    transposeW<<<dim3(Dd / 32, Hh / 32), tb, 0, stream>>>(Wout, WoutT, Hh, Dd);

    initstate<<<(BH_ + 255) / 256, 256, 0, stream>>>(lstate, idrift, xx, aa, bbp, ppp, cc, drift, scal);

    GemmP p1 = {};
    p1.A[0] = Acat; p1.W[0] = WinT; p1.mode[0] = M_IN;
    p1.M = Bb; p1.N = Hh; p1.K = 2 * Dd;
    p1.done = doneptr;
    p1.bias = b_in; p1.mk = mix_k; p1.mv = mix_v; p1.mr = mix_r; p1.mk2v = mix_k2; p1.mr2v = mix_r2;
    p1.xx = xx; p1.cc = cc; p1.liF = Li;
    p1.o1 = Xk; p1.o2 = Xv; p1.o3 = Xr; p1.o4 = Xk2; p1.o5 = Xr2;

    GemmP p2 = {};
    p2.A[0] = Xk; p2.A[1] = Xv; p2.A[2] = Xr;
    p2.W[0] = WkT; p2.W[1] = WvT; p2.W[2] = WrT;
    p2.mode[0] = M_F32; p2.mode[1] = M_F32; p2.mode[2] = M_F32;
    p2.dst[0] = Kp; p2.dst[1] = Vp; p2.dst[2] = Rp;
    p2.M = Bb; p2.N = Hh; p2.K = Hh;
    p2.done = doneptr;

    GemmP p3 = {};
    p3.A[0] = Rw; p3.A[1] = Xr2; p3.A[2] = Xk2;
    p3.W[0] = WoT; p3.W[1] = Wr2T; p3.W[2] = Wk2T;
    p3.mode[0] = M_F32; p3.mode[1] = M_SIG; p3.mode[2] = M_SQRELU;
    p3.dst[0] = Tm; p3.dst[1] = R2; p3.dst[2] = Kk;
    p3.M = Bb; p3.N = Hh; p3.K = Hh;
    p3.done = doneptr;

    GemmP p4 = {};
    p4.A[0] = Kk; p4.W[0] = Wv2T; p4.mode[0] = M_OUT; p4.dst[0] = Ob;
    p4.M = Bb; p4.N = Hh; p4.K = Hh;
    p4.f1 = Tm; p4.f2 = R2;
    p4.done = doneptr;

    GemmP p5 = {};
    p5.A[0] = Ob; p5.W[0] = WdT; p5.mode[0] = M_DRIFT;
    p5.M = Bb; p5.N = Dd; p5.K = Hh;
    p5.drift = drift; p5.accAbs = accAbs; p5.accSq = accSq;
    p5.scal = scal; p5.nticket = (Dd / 128) * (Bb / 128);
    p5.done = doneptr;

    dim3 gH(Hh / 128, Bb / 128, 1);      // 16 x 4 = 64 blocks
    dim3 gH3(Hh / 128, Bb / 128, 3);     // 192 blocks
    dim3 gD(Dd / 128, Bb / 128, 1);      // 32 blocks

    for (int s = 0; s < 8; ++s) {
        prep<<<(BD_ + 255) / 256, 256, 0, stream>>>(enc, sc, drift, Acat, doneptr);
        gemm128<<<gH, 256, 0, stream>>>(p1);
        gemm128<<<gH3, 256, 0, stream>>>(p2);
        mix1<<<(BH_ + 255) / 256, 256, 0, stream>>>(Kp, Vp, Rp, aa, bbp, ppp, xx, cc, Li,
                                                    tfirst, tdec, Rw, nullptr, nullptr, doneptr);
        gemm128<<<gH3, 256, 0, stream>>>(p3);
        gemm128<<<gH, 256, 0, stream>>>(p4);
        gemm128<<<gD, 256, 0, stream>>>(p5);   // ticket-folded stepfin
    }

    // ---- final commit step (no done guard; ORIGINAL l_state) ----
    float* stateOut = dout + BD_;

    prep<<<(BD_ + 255) / 256, 256, 0, stream>>>(enc, sc, drift, Acat, nullptr);

    GemmP f1p = p1;
    f1p.done = nullptr; f1p.lstate = lstate; f1p.stateOut = stateOut;
    gemm128<<<gH, 256, 0, stream>>>(f1p);

    GemmP f2p = p2; f2p.done = nullptr;
    gemm128<<<gH3, 256, 0, stream>>>(f2p);

    mix1<<<(BH_ + 255) / 256, 256, 0, stream>>>(Kp, Vp, Rp, aa, bbp, ppp, xx, cc, Li,
                                                tfirst, tdec, Rw, lstate, stateOut, nullptr);

    GemmP f3p = p3; f3p.done = nullptr;
    gemm128<<<gH3, 256, 0, stream>>>(f3p);

    GemmP f4p = p4; f4p.done = nullptr;
    gemm128<<<gH, 256, 0, stream>>>(f4p);

    GemmP f5p = {};
    f5p.A[0] = Ob; f5p.W[0] = WoutT; f5p.mode[0] = M_FINAL;
    f5p.M = Bb; f5p.N = Dd; f5p.K = Hh;
    f5p.enc = enc; f5p.bout = b_out; f5p.dout = dout;
    gemm128<<<gD, 256, 0, stream>>>(f5p);

    tailk<<<(BD_ + 255) / 256, 256, 0, stream>>>(scal, drift, dout);
}

// Round 4
// 1685.729 us; speedup vs baseline: 2.0319x; 2.0319x over previous
//
#include <hip/hip_runtime.h>
#include <hip/hip_bf16.h>

#define Bb 512
#define Dd 1024
#define Hh 2048
#define BH_ (Bb*Hh)
#define BD_ (Bb*Dd)

typedef unsigned short u16;
typedef __attribute__((ext_vector_type(8))) short short8;
typedef __attribute__((ext_vector_type(4))) float f32x4;

enum { M_F32 = 0, M_IN, M_SIG, M_SQRELU, M_OUT, M_DRIFT, M_FINAL };

struct GemmP {
    const u16* A[3];
    const u16* W[3];     // transposed weights, N x K, bf16
    void* dst[3];
    int mode[3];
    int M, N, K;
    const int* done;
    // epilogue extras
    const float* bias;
    const float* mk; const float* mv; const float* mr; const float* mk2v; const float* mr2v;
    const float* xx; const float* cc;     // planar shadow state (loop)
    const float* lstate;                  // original interleaved state (final) or null
    float* liF;                           // Li plane (loop)
    float* stateOut;                      // d_out next_state base (final)
    u16 *o1, *o2, *o3, *o4, *o5;          // Xk,Xv,Xr,Xk2,Xr2
    const float* f1; const float* f2;     // Tm, R2
    float* drift; float* accAbs; float* accSq;
    float* scal; int nticket;             // ticket-folded stepfin (M_DRIFT only)
    const float* enc; const float* bout; float* dout;
};

// ---- 64x64 tile, 512 threads (8 waves), in-block split-K x2, BK=128 ----
// Wave w: wq=w&3 picks 32x32 quadrant (wm,wn), kg=w>>2 picks K-half of each
// BK=128 slab. Partials merged through LDS after the K loop; wave-group 0
// runs the epilogue (identical to the R2-passing epilogue).
__global__ __launch_bounds__(512, 4) void gemm_sk(GemmP p) {
    if (p.done && *(volatile const int*)p.done) return;
    const int z = blockIdx.z;
    const u16* __restrict__ A = p.A[z];
    const u16* __restrict__ W = p.W[z];
    const int Kd = p.K;
    const int m0 = blockIdx.y * 64, n0 = blockIdx.x * 64;

    __shared__ alignas(16) u16 As[64 * 136];   // 17408 B
    __shared__ alignas(16) u16 Bs[64 * 136];

    const int t = threadIdx.x;
    const int l = t & 63, w = t >> 6;
    const int lane16 = l & 15, quad = l >> 4;
    const int wq = w & 3, kg = w >> 2;
    const int wm = wq & 1, wn = wq >> 1;
    const int srow = t >> 3, scp = t & 7;      // staging: row 0..63, 16B-chunk 0..7

    f32x4 zero = {0.f, 0.f, 0.f, 0.f};
    f32x4 acc[2][2];
    acc[0][0] = zero; acc[0][1] = zero; acc[1][0] = zero; acc[1][1] = zero;

    const u16* ap = A + (size_t)(m0 + srow) * Kd + scp * 8;
    const u16* bp = W + (size_t)(n0 + srow) * Kd + scp * 8;

    uint4 ra0 = *(const uint4*)(const void*)(ap);
    uint4 ra1 = *(const uint4*)(const void*)(ap + 64);
    uint4 rb0 = *(const uint4*)(const void*)(bp);
    uint4 rb1 = *(const uint4*)(const void*)(bp + 64);

    for (int k0 = 0; k0 < Kd; k0 += 128) {
        *(uint4*)(void*)&As[srow * 136 + scp * 8]      = ra0;
        *(uint4*)(void*)&As[srow * 136 + scp * 8 + 64] = ra1;
        *(uint4*)(void*)&Bs[srow * 136 + scp * 8]      = rb0;
        *(uint4*)(void*)&Bs[srow * 136 + scp * 8 + 64] = rb1;
        __syncthreads();
        if (k0 + 128 < Kd) {
            ra0 = *(const uint4*)(const void*)(ap + k0 + 128);
            ra1 = *(const uint4*)(const void*)(ap + k0 + 192);
            rb0 = *(const uint4*)(const void*)(bp + k0 + 128);
            rb1 = *(const uint4*)(const void*)(bp + k0 + 192);
        }
        const int kb = kg * 64;
#pragma unroll
        for (int kc = 0; kc < 64; kc += 32) {
            const int col = kb + kc + quad * 8;
            short8 af0 = *(const short8*)(const void*)&As[(wm * 32 + lane16) * 136 + col];
            short8 af1 = *(const short8*)(const void*)&As[(wm * 32 + 16 + lane16) * 136 + col];
            short8 bf0 = *(const short8*)(const void*)&Bs[(wn * 32 + lane16) * 136 + col];
            short8 bf1 = *(const short8*)(const void*)&Bs[(wn * 32 + 16 + lane16) * 136 + col];
            acc[0][0] = __builtin_amdgcn_mfma_f32_16x16x32_bf16(af0, bf0, acc[0][0], 0, 0, 0);
            acc[0][1] = __builtin_amdgcn_mfma_f32_16x16x32_bf16(af0, bf1, acc[0][1], 0, 0, 0);
            acc[1][0] = __builtin_amdgcn_mfma_f32_16x16x32_bf16(af1, bf0, acc[1][0], 0, 0, 0);
            acc[1][1] = __builtin_amdgcn_mfma_f32_16x16x32_bf16(af1, bf1, acc[1][1], 0, 0, 0);
        }
        __syncthreads();
    }

    // ---- cross-wave-group partial merge via LDS (reuse As; 17 fl/lane pad) ----
    float* red = (float*)As;
    const int rbase = wq * 1088 + l * 17;
    if (kg == 1) {
#pragma unroll
        for (int sm = 0; sm < 2; ++sm)
#pragma unroll
            for (int sn = 0; sn < 2; ++sn)
#pragma unroll
                for (int i = 0; i < 4; ++i)
                    red[rbase + (sm * 2 + sn) * 4 + i] = acc[sm][sn][i];
    }
    __syncthreads();
    if (kg == 0) {
#pragma unroll
        for (int sm = 0; sm < 2; ++sm)
#pragma unroll
            for (int sn = 0; sn < 2; ++sn)
#pragma unroll
                for (int i = 0; i < 4; ++i)
                    acc[sm][sn][i] += red[rbase + (sm * 2 + sn) * 4 + i];
    }

    const int mode = p.mode[z];
    float sabs = 0.f, ssq = 0.f;
    if (kg == 0) {
#pragma unroll
        for (int sm = 0; sm < 2; ++sm)
#pragma unroll
            for (int sn = 0; sn < 2; ++sn)
#pragma unroll
                for (int i = 0; i < 4; ++i) {
                    const int m = m0 + wm * 32 + sm * 16 + quad * 4 + i;
                    const int n = n0 + wn * 32 + sn * 16 + lane16;
                    const size_t idx = (size_t)m * p.N + n;
                    const float v = acc[sm][sn][i];
                    if (mode == M_F32) {
                        ((float*)p.dst[z])[idx] = v;
                    } else if (mode == M_IN) {
                        float li = fminf(fmaxf(v + p.bias[n], -50.f), 50.f);
                        float xxv, ccv;
                        if (p.lstate) { xxv = p.lstate[idx * 5 + 0]; ccv = p.lstate[idx * 5 + 4]; }
                        else { xxv = p.xx[idx]; ccv = p.cc[idx]; }
                        float mk = p.mk[n], mv = p.mv[n], mr = p.mr[n], mk2 = p.mk2v[n], mr2 = p.mr2v[n];
                        ((__hip_bfloat16*)p.o1)[idx] = __float2bfloat16(li * mk + xxv * (1.f - mk));
                        ((__hip_bfloat16*)p.o2)[idx] = __float2bfloat16(li * mv + xxv * (1.f - mv));
                        ((__hip_bfloat16*)p.o3)[idx] = __float2bfloat16(li * mr + xxv * (1.f - mr));
                        ((__hip_bfloat16*)p.o4)[idx] = __float2bfloat16(li * mk2 + ccv * (1.f - mk2));
                        ((__hip_bfloat16*)p.o5)[idx] = __float2bfloat16(li * mr2 + ccv * (1.f - mr2));
                        if (p.lstate) { p.stateOut[idx * 5 + 0] = li; p.stateOut[idx * 5 + 4] = li; }
                        else p.liF[idx] = li;
                    } else if (mode == M_SIG) {
                        ((float*)p.dst[z])[idx] = 1.f / (1.f + __expf(-v));
                    } else if (mode == M_SQRELU) {
                        float r = fmaxf(v, 0.f);
                        ((__hip_bfloat16*)p.dst[z])[idx] = __float2bfloat16(r * r);
                    } else if (mode == M_OUT) {
                        ((__hip_bfloat16*)p.dst[z])[idx] = __float2bfloat16(p.f1[idx] + p.f2[idx] * v);
                    } else if (mode == M_DRIFT) {
                        float d = tanhf(v);
                        float nd = fminf(fmaxf(p.drift[idx] + d, -5.f), 5.f);
                        p.drift[idx] = nd;
                        sabs += fabsf(d);
                        ssq += nd * nd;
                    } else { // M_FINAL
                        p.dout[idx] = p.enc[idx] + v + p.bout[n];
                    }
                }
    }
    if (mode == M_DRIFT) {
        if (kg == 0) {
#pragma unroll
            for (int off = 32; off > 0; off >>= 1) {
                sabs += __shfl_down(sabs, off, 64);
                ssq += __shfl_down(ssq, off, 64);
            }
            if (l == 0) { atomicAdd(p.accAbs, sabs); atomicAdd(p.accSq, ssq); }
        }
        __syncthreads();
        if (t == 0) {   // last-block ticket performs the per-step scalar finalize
            __threadfence();
            int v = atomicAdd((int*)(p.scal + 5), 1);
            if (v == p.nticket - 1) {
                volatile float* s = p.scal;
                float hinge = fminf(fmaxf(s[4] / (float)Bb - 0.1f, 0.f), 100.f);
                s[1] = s[1] + hinge;
                s[2] = s[2] + 1.f;
                if (s[3] / (float)BD_ < 0.01f) ((volatile int*)p.scal)[0] = 1;
                s[3] = 0.f; s[4] = 0.f;
                ((volatile int*)p.scal)[5] = 0;
            }
        }
    }
}

// ---------------- transpose f32 (KxN) -> bf16 (NxK) ----------------
__global__ void transposeW(const float* __restrict__ src, u16* __restrict__ dst, int K, int N) {
    __shared__ float tile[32][33];
    int kt = blockIdx.y * 32, nt = blockIdx.x * 32;
    int tx = threadIdx.x, ty = threadIdx.y;
#pragma unroll
    for (int j = 0; j < 4; j++)
        tile[ty + j * 8][tx] = src[(size_t)(kt + ty + j * 8) * N + nt + tx];
    __syncthreads();
    __hip_bfloat16* d = (__hip_bfloat16*)dst;
#pragma unroll
    for (int j = 0; j < 4; j++)
        d[(size_t)(nt + ty + j * 8) * K + kt + tx] = __float2bfloat16(tile[tx][ty + j * 8]);
}

// ---------------- per-call init: planarize state, copy drift, zero scalars ----------------
__global__ void initstate(const float* __restrict__ lstate, const float* __restrict__ idrift,
                          float* xx, float* aa, float* bb, float* pp, float* cc,
                          float* drift, float* scal) {
    int i = blockIdx.x * 256 + threadIdx.x;
    if (i < BH_) {
        const float* s = lstate + (size_t)i * 5;
        xx[i] = s[0]; aa[i] = s[1]; bb[i] = s[2]; pp[i] = s[3]; cc[i] = s[4];
    }
    if (i < BD_) drift[i] = idrift[i];
    if (i == 0) {
        ((int*)scal)[0] = 0; scal[1] = 0.f; scal[2] = 0.f; scal[3] = 0.f; scal[4] = 0.f;
        ((int*)scal)[5] = 0;
    }
}

// ---------------- build A = [enc, sc + drift] in bf16 ----------------
__global__ void prep(const float* __restrict__ enc, const float* __restrict__ sc,
                     const float* __restrict__ drift, u16* __restrict__ Acat, const int* done) {
    if (done && *(volatile const int*)done) return;
    int i = blockIdx.x * 256 + threadIdx.x;
    if (i >= BD_) return;
    int m = i >> 10, d = i & 1023;
    __hip_bfloat16* Ab = (__hip_bfloat16*)Acat;
    Ab[(size_t)m * 2048 + d] = __float2bfloat16(enc[i]);
    Ab[(size_t)m * 2048 + 1024 + d] = __float2bfloat16(sc[i] + drift[i]);
}

// ---------------- RWKV wkv + state update ----------------
__global__ void mix1(const float* __restrict__ Kp, const float* __restrict__ Vp,
                     const float* __restrict__ Rp,
                     float* aa, float* bb, float* pp, float* xx, float* cc,
                     const float* __restrict__ Li,
                     const float* __restrict__ tf, const float* __restrict__ td,
                     u16* __restrict__ rwkv,
                     const float* __restrict__ lstate, float* stateOut,
                     const int* done) {
    if (done && *(volatile const int*)done) return;
    int i = blockIdx.x * 256 + threadIdx.x;
    if (i >= BH_) return;
    int h = i & (Hh - 1);
    float k = Kp[i], v = Vp[i], rpre = Rp[i];
    float a, b, P;
    if (lstate) { a = lstate[(size_t)i * 5 + 1]; b = lstate[(size_t)i * 5 + 2]; P = lstate[(size_t)i * 5 + 3]; }
    else { a = aa[i]; b = bb[i]; P = pp[i]; }
    float r = 1.f / (1.f + __expf(-rpre));
    float ww = tf[h] + k;
    float q = fmaxf(P, ww);
    float e1 = __expf(P - q), e2 = __expf(ww - q);
    float wkv = (e1 * a + e2 * v) / (e1 * b + e2);
    ((__hip_bfloat16*)rwkv)[i] = __float2bfloat16(r * wkv);
    float ww2 = P - __expf(td[h]);
    float q2 = fmaxf(ww2, k);
    float e1b = __expf(ww2 - q2), e2b = __expf(k - q2);
    float na = fminf(fmaxf(e1b * a + e2b * v, -50.f), 50.f);
    float nb = fminf(fmaxf(e1b * b + e2b, -50.f), 50.f);
    float nq = fminf(fmaxf(q2, -50.f), 50.f);
    if (lstate) {
        stateOut[(size_t)i * 5 + 1] = na; stateOut[(size_t)i * 5 + 2] = nb; stateOut[(size_t)i * 5 + 3] = nq;
    } else {
        aa[i] = na; bb[i] = nb; pp[i] = nq;
        float li = Li[i];
        xx[i] = li; cc[i] = li;
    }
}

// ---------------- tail: commitment scalar + drift copy ----------------
__global__ void tailk(const float* __restrict__ scal, const float* __restrict__ drift, float* __restrict__ dout) {
    int i = blockIdx.x * 256 + threadIdx.x;
    const size_t OC = (size_t)BD_ + (size_t)5 * BH_;
    if (i == 0) dout[OC] = scal[1] / fmaxf(scal[2], 1.f);
    if (i < BD_) dout[OC + 1 + i] = drift[i];
}

extern "C" void kernel_launch(void* const* d_in, const int* in_sizes, int n_in,
                              void* d_out, int out_size, void* d_ws, size_t ws_size,
                              hipStream_t stream) {
    const float* enc    = (const float*)d_in[0];
    const float* sc     = (const float*)d_in[1];
    const float* lstate = (const float*)d_in[2];
    const float* idrift = (const float*)d_in[3];
    const float* Win    = (const float*)d_in[4];
    const float* b_in   = (const float*)d_in[5];
    const float* Wdrift = (const float*)d_in[6];
    const float* Wout   = (const float*)d_in[7];
    const float* b_out  = (const float*)d_in[8];
    const float* mix_k  = (const float*)d_in[9];
    const float* mix_v  = (const float*)d_in[10];
    const float* mix_r  = (const float*)d_in[11];
    const float* mix_k2 = (const float*)d_in[12];
    const float* mix_r2 = (const float*)d_in[13];
    const float* tdec   = (const float*)d_in[14];
    const float* tfirst = (const float*)d_in[15];
    const float* Wk  = (const float*)d_in[16];
    const float* Wv  = (const float*)d_in[17];
    const float* Wr  = (const float*)d_in[18];
    const float* Wo  = (const float*)d_in[19];
    const float* Wk2 = (const float*)d_in[20];
    const float* Wv2 = (const float*)d_in[21];
    const float* Wr2 = (const float*)d_in[22];
    float* dout = (float*)d_out;

    const size_t BHs = (size_t)Bb * Hh;
    const size_t BDs = (size_t)Bb * Dd;

    const size_t need_f32 = 9 * BHs + BDs + 16;
    const size_t need_u16 = (size_t)2 * Dd * Hh + 7 * (size_t)Hh * Hh + 2 * (size_t)Hh * Dd + 8 * BHs;
    const size_t need_bytes = need_f32 * 4 + need_u16 * 2;
    if (ws_size < need_bytes) return;

    float* f = (float*)d_ws;
    float* xx  = f;
    float* aa  = xx + BHs;
    float* bbp = aa + BHs;
    float* ppp = bbp + BHs;
    float* cc  = ppp + BHs;
    float* Li  = cc + BHs;
    float* Kp  = Li + BHs;
    float* Vp  = Kp + BHs;
    float* Rp  = Vp + BHs;
    float* Tm  = Kp;    // alias: Kp dead after mix1, Tm written in p3
    float* R2  = Vp;    // alias: Vp dead after mix1, R2 written in p3
    float* drift = Rp + BHs;
    float* scal  = drift + BDs;
    u16* u = (u16*)(scal + 16);
    u16* WinT  = u; u += (size_t)2 * Dd * Hh;
    u16* WkT   = u; u += (size_t)Hh * Hh;
    u16* WvT   = u; u += (size_t)Hh * Hh;
    u16* WrT   = u; u += (size_t)Hh * Hh;
    u16* WoT   = u; u += (size_t)Hh * Hh;
    u16* Wk2T  = u; u += (size_t)Hh * Hh;
    u16* Wv2T  = u; u += (size_t)Hh * Hh;
    u16* Wr2T  = u; u += (size_t)Hh * Hh;
    u16* WdT   = u; u += (size_t)Hh * Dd;
    u16* WoutT = u; u += (size_t)Hh * Dd;
    u16* Acat = u; u += BHs;
    u16* Xk   = u; u += BHs;
    u16* Xv   = u; u += BHs;
    u16* Xr   = u; u += BHs;
    u16* Xk2  = u; u += BHs;
    u16* Xr2  = u; u += BHs;
    u16* Rw   = u; u += BHs;
    u16* Kk   = u; u += BHs;
    u16* Ob   = Acat;   // alias: Acat read only by p1; Ob written at p4, read at p5

    int* doneptr = (int*)scal;
    float* accAbs = scal + 3;
    float* accSq  = scal + 4;

    dim3 tb(32, 8);
    transposeW<<<dim3(Hh / 32, (2 * Dd) / 32), tb, 0, stream>>>(Win, WinT, 2 * Dd, Hh);
    transposeW<<<dim3(Hh / 32, Hh / 32), tb, 0, stream>>>(Wk,  WkT,  Hh, Hh);
    transposeW<<<dim3(Hh / 32, Hh / 32), tb, 0, stream>>>(Wv,  WvT,  Hh, Hh);
    transposeW<<<dim3(Hh / 32, Hh / 32), tb, 0, stream>>>(Wr,  WrT,  Hh, Hh);
    transposeW<<<dim3(Hh / 32, Hh / 32), tb, 0, stream>>>(Wo,  WoT,  Hh, Hh);
    transposeW<<<dim3(Hh / 32, Hh / 32), tb, 0, stream>>>(Wk2, Wk2T, Hh, Hh);
    transposeW<<<dim3(Hh / 32, Hh / 32), tb, 0, stream>>>(Wv2, Wv2T, Hh, Hh);
    transposeW<<<dim3(Hh / 32, Hh / 32), tb, 0, stream>>>(Wr2, Wr2T, Hh, Hh);
    transposeW<<<dim3(Dd / 32, Hh / 32), tb, 0, stream>>>(Wdrift, WdT, Hh, Dd);
    transposeW<<<dim3(Dd / 32, Hh / 32), tb, 0, stream>>>(Wout, WoutT, Hh, Dd);

    initstate<<<(BH_ + 255) / 256, 256, 0, stream>>>(lstate, idrift, xx, aa, bbp, ppp, cc, drift, scal);

    GemmP p1 = {};
    p1.A[0] = Acat; p1.W[0] = WinT; p1.mode[0] = M_IN;
    p1.M = Bb; p1.N = Hh; p1.K = 2 * Dd;
    p1.done = doneptr;
    p1.bias = b_in; p1.mk = mix_k; p1.mv = mix_v; p1.mr = mix_r; p1.mk2v = mix_k2; p1.mr2v = mix_r2;
    p1.xx = xx; p1.cc = cc; p1.liF = Li;
    p1.o1 = Xk; p1.o2 = Xv; p1.o3 = Xr; p1.o4 = Xk2; p1.o5 = Xr2;

    GemmP p2 = {};
    p2.A[0] = Xk; p2.A[1] = Xv; p2.A[2] = Xr;
    p2.W[0] = WkT; p2.W[1] = WvT; p2.W[2] = WrT;
    p2.mode[0] = M_F32; p2.mode[1] = M_F32; p2.mode[2] = M_F32;
    p2.dst[0] = Kp; p2.dst[1] = Vp; p2.dst[2] = Rp;
    p2.M = Bb; p2.N = Hh; p2.K = Hh;
    p2.done = doneptr;

    GemmP p3 = {};
    p3.A[0] = Rw; p3.A[1] = Xr2; p3.A[2] = Xk2;
    p3.W[0] = WoT; p3.W[1] = Wr2T; p3.W[2] = Wk2T;
    p3.mode[0] = M_F32; p3.mode[1] = M_SIG; p3.mode[2] = M_SQRELU;
    p3.dst[0] = Tm; p3.dst[1] = R2; p3.dst[2] = Kk;
    p3.M = Bb; p3.N = Hh; p3.K = Hh;
    p3.done = doneptr;

    GemmP p4 = {};
    p4.A[0] = Kk; p4.W[0] = Wv2T; p4.mode[0] = M_OUT; p4.dst[0] = Ob;
    p4.M = Bb; p4.N = Hh; p4.K = Hh;
    p4.f1 = Tm; p4.f2 = R2;
    p4.done = doneptr;

    GemmP p5 = {};
    p5.A[0] = Ob; p5.W[0] = WdT; p5.mode[0] = M_DRIFT;
    p5.M = Bb; p5.N = Dd; p5.K = Hh;
    p5.drift = drift; p5.accAbs = accAbs; p5.accSq = accSq;
    p5.scal = scal; p5.nticket = (Dd / 64) * (Bb / 64);   // 128
    p5.done = doneptr;

    dim3 gH(Hh / 64, Bb / 64, 1);      // 32 x 8 = 256 blocks
    dim3 gH3(Hh / 64, Bb / 64, 3);     // 768 blocks
    dim3 gD(Dd / 64, Bb / 64, 1);      // 128 blocks

    for (int s = 0; s < 8; ++s) {
        prep<<<(BD_ + 255) / 256, 256, 0, stream>>>(enc, sc, drift, Acat, doneptr);
        gemm_sk<<<gH, 512, 0, stream>>>(p1);
        gemm_sk<<<gH3, 512, 0, stream>>>(p2);
        mix1<<<(BH_ + 255) / 256, 256, 0, stream>>>(Kp, Vp, Rp, aa, bbp, ppp, xx, cc, Li,
                                                    tfirst, tdec, Rw, nullptr, nullptr, doneptr);
        gemm_sk<<<gH3, 512, 0, stream>>>(p3);
        gemm_sk<<<gH, 512, 0, stream>>>(p4);
        gemm_sk<<<gD, 512, 0, stream>>>(p5);   // ticket-folded stepfin
    }

    // ---- final commit step (no done guard; ORIGINAL l_state) ----
    float* stateOut = dout + BD_;

    prep<<<(BD_ + 255) / 256, 256, 0, stream>>>(enc, sc, drift, Acat, nullptr);

    GemmP f1p = p1;
    f1p.done = nullptr; f1p.lstate = lstate; f1p.stateOut = stateOut;
    gemm_sk<<<gH, 512, 0, stream>>>(f1p);

    GemmP f2p = p2; f2p.done = nullptr;
    gemm_sk<<<gH3, 512, 0, stream>>>(f2p);

    mix1<<<(BH_ + 255) / 256, 256, 0, stream>>>(Kp, Vp, Rp, aa, bbp, ppp, xx, cc, Li,
                                                tfirst, tdec, Rw, lstate, stateOut, nullptr);

    GemmP f3p = p3; f3p.done = nullptr;
    gemm_sk<<<gH3, 512, 0, stream>>>(f3p);

    GemmP f4p = p4; f4p.done = nullptr;
    gemm_sk<<<gH, 512, 0, stream>>>(f4p);

    GemmP f5p = {};
    f5p.A[0] = Ob; f5p.W[0] = WoutT; f5p.mode[0] = M_FINAL;
    f5p.M = Bb; f5p.N = Dd; f5p.K = Hh;
    f5p.enc = enc; f5p.bout = b_out; f5p.dout = dout;
    gemm_sk<<<gD, 512, 0, stream>>>(f5p);

    tailk<<<(BD_ + 255) / 256, 256, 0, stream>>>(scal, drift, dout);
}